// Round 5
// baseline (1237.031 us; speedup 1.0000x reference)
//
#include <hip/hip_runtime.h>

// QueryPinnedHopfieldLayer on MI355X (gfx950). fp32 in/out; internal K/V bf16.
// d_out (134.2 MB) doubles as scratch: ln_mb bf16 (76.8 MB, aliased by z after
// gemm), K (25.6), V (25.6), wkv bf16 (0.79), bmax (0.1).
//
// Round-9 changes vs round-8 (1233 us; entsolve_k = 3x232.5 us, VALUBusy 0.6%):
//  ROOT CAUSE: entmax support >> ECAP in steps 2-3 (xi ~ convex combo of all V
//  -> z spread ~1e-3 -> near-uniform entmax, support ~ all 50000). The LDS
//  candidate list overflowed and Newton fell back to up-to-24 full-GN global
//  scans on 32 CUs (~9 us each) = 232 us.
//  FIX: entsolve_k rebuilt: NO candidate list, NO Newton. Two-level histogram
//  (256 bins then 256 sub-bins) with SHIFTED per-bin moments (d = u - edge;
//  small magnitudes -> no cancellation), stable incremental frame-shift scans,
//  and a closed-form quadratic at the final 1/65536-wide bracket
//  (error <= ~6e-6 on tau). Exactly 2 passes over z per bh.
//  Tie-regime contention: per-thread run-length cache + 8 bank-staggered
//  histogram replicas (row stride 261 -> replicas on distinct LDS banks).

typedef unsigned short u16;
typedef unsigned int u32;

typedef __bf16 bf16x8 __attribute__((ext_vector_type(8)));
typedef float f32x4 __attribute__((ext_vector_type(4)));

#define GN 50000
#define NH 4
#define HD 64
#define NB 8
#define MD 768
#define HID 2048
#define NBLK 782
#define NB1 256
#define W1F (1.f/256.f)
#define W2F (1.f/65536.f)

__device__ __forceinline__ float bf2f(u16 u) {
  union { u32 i; float f; } v; v.i = ((u32)u) << 16; return v.f;
}
__device__ __forceinline__ u16 f2bf(float f) {
  u32 x = __float_as_uint(f);
  u32 r = (x + 0x7FFFu + ((x >> 16) & 1u)) >> 16;
  return (u16)r;
}

// ---- scratch layout inside d_out (bytes; 16B aligned) ----
#define LN_OFF    0ull           // 50000*768 bf16 = 76.8 MB (dead after gemm)
#define Z_OFF     0ull           // 32*50000 f32 = 6.4 MB (aliases LN)
#define K_OFF     76800000ull    // 4*50000*64 bf16
#define V_OFF     102400000ull
#define WKV_OFF   128000000ull   // 512*768 bf16
#define BMAX_OFF  128786432ull   // 32*782 f32 -> ends 128.9 MB < 134.2 MB
// ---- small state in d_ws (proven >= 82944 B) ----
#define XIA_OFF   0u
#define XIB_OFF   8192u
#define T_OFF     16384u
#define BETA_OFF  16512u
#define OUTS_OFF  16640u         // 8*2048 f32 -> ends 82176 (< 82944)

// ---------------- kernels ----------------

// LN(memory_bank) -> bf16, one wave per row (row held in registers)
__global__ __launch_bounds__(256) void row_ln(const float* __restrict__ mb,
                                              const float* __restrict__ gm,
                                              const float* __restrict__ bm,
                                              u16* __restrict__ ln) {
  int row = blockIdx.x * 4 + (threadIdx.x >> 6);
  int lane = threadIdx.x & 63;
  const float4* p4 = (const float4*)(mb + (size_t)row * MD);
  float4 v[3];
  float s = 0.f, ss = 0.f;
#pragma unroll
  for (int j = 0; j < 3; ++j) {
    v[j] = p4[lane + 64 * j];
    s += v[j].x + v[j].y + v[j].z + v[j].w;
    ss += v[j].x * v[j].x + v[j].y * v[j].y + v[j].z * v[j].z + v[j].w * v[j].w;
  }
  for (int o = 32; o > 0; o >>= 1) { s += __shfl_down(s, o); ss += __shfl_down(ss, o); }
  s = __shfl(s, 0); ss = __shfl(ss, 0);
  float m = s * (1.f / 768.f);
  float var = ss * (1.f / 768.f) - m * m;
  float r = rsqrtf(fmaxf(var, 0.f) + 1e-5f);
#pragma unroll
  for (int j = 0; j < 3; ++j) {
    float4 g = ((const float4*)gm)[lane + 64 * j];
    float4 b = ((const float4*)bm)[lane + 64 * j];
    ushort4 o4;
    o4.x = f2bf((v[j].x - m) * r * g.x + b.x);
    o4.y = f2bf((v[j].y - m) * r * g.y + b.y);
    o4.z = f2bf((v[j].z - m) * r * g.z + b.z);
    o4.w = f2bf((v[j].w - m) * r * g.w + b.w);
    *(ushort4*)(ln + (size_t)row * MD + (lane + 64 * j) * 4) = o4;
  }
}

// Wk|Wv fp32 -> bf16 (512x768 flat)
__global__ __launch_bounds__(256) void wconv(const float* __restrict__ Wk,
                                             const float* __restrict__ Wv,
                                             u16* __restrict__ wkv) {
  int i = blockIdx.x * 256 + threadIdx.x;   // float4 index, 98304 total
  float4 v = (i < 49152) ? ((const float4*)Wk)[i] : ((const float4*)Wv)[i - 49152];
  ushort4 o;
  o.x = f2bf(v.x); o.y = f2bf(v.y); o.z = f2bf(v.z); o.w = f2bf(v.w);
  ((ushort4*)wkv)[i] = o;
}

__global__ __launch_bounds__(256) void qprep(const float* __restrict__ qe, const float* __restrict__ Wq,
                                             const float* __restrict__ gq, const float* __restrict__ bq,
                                             const float* __restrict__ lb, float* __restrict__ xi0,
                                             float* __restrict__ beta) {
  int b = blockIdx.x, t = threadIdx.x;
  __shared__ float nq[768];
  __shared__ float w1[4], w2[4];
  float s = 0.f, ss = 0.f;
  for (int j = t; j < 768; j += 256) { float x = qe[b * 768 + j]; s += x; ss += x * x; }
  for (int o = 32; o > 0; o >>= 1) { s += __shfl_down(s, o); ss += __shfl_down(ss, o); }
  if ((t & 63) == 0) { w1[t >> 6] = s; w2[t >> 6] = ss; }
  __syncthreads();
  float S = w1[0] + w1[1] + w1[2] + w1[3];
  float SS = w2[0] + w2[1] + w2[2] + w2[3];
  float m = S * (1.f / 768.f);
  float var = SS * (1.f / 768.f) - m * m;
  float r = rsqrtf(fmaxf(var, 0.f) + 1e-5f);
  for (int j = t; j < 768; j += 256) {
    float x = qe[b * 768 + j];
    nq[j] = (x - m) * r * gq[j] + bq[j];
  }
  __syncthreads();
  const float4* wrow = (const float4*)(Wq + (size_t)t * 768);
  float acc = 0.f;
  for (int k = 0; k < 192; ++k) {
    float4 wv = wrow[k];
    acc += nq[k * 4] * wv.x + nq[k * 4 + 1] * wv.y + nq[k * 4 + 2] * wv.z + nq[k * 4 + 3] * wv.w;
  }
  xi0[b * 256 + t] = acc;
  if (b == 0 && t < 4) beta[t] = expf(lb[t]);
}

// C = ln_mb(bf16) @ wkv^T. BM=128, BN=256, BK=64; 8 waves each 64x64.
__global__ __launch_bounds__(512) void gemm_kv(const u16* __restrict__ ln,
                                               const u16* __restrict__ wkv,
                                               u16* __restrict__ Kbuf, u16* __restrict__ Vbuf) {
  __shared__ u16 As[128][72];
  __shared__ u16 Bs[256][72];
  int t = threadIdx.x;
  int i0 = blockIdx.x * 128;
  int j0 = blockIdx.y;          // 0 -> K, 1 -> V
  int jb = j0 * 256;
  u16* obuf = j0 ? Vbuf : Kbuf;

  int w = t >> 6, lane = t & 63;
  int quad = lane >> 4, l16 = lane & 15;
  int wm = (w >> 2) * 64;       // M half owned by this wave
  int wn = (w & 3) * 64;        // N quarter owned by this wave

  f32x4 acc[4][4];
#pragma unroll
  for (int a = 0; a < 4; ++a)
#pragma unroll
    for (int b = 0; b < 4; ++b) { f32x4 zz = {0.f, 0.f, 0.f, 0.f}; acc[a][b] = zz; }

  for (int k0 = 0; k0 < 768; k0 += 64) {
    // stage A: 128x64 bf16 = 1024 16B chunks, 512 thr -> 2 each
#pragma unroll
    for (int cc = 0; cc < 2; ++cc) {
      int c = t + cc * 512;
      int r = c >> 3, seg = c & 7;
      int row = i0 + r;
      uint4 val = make_uint4(0, 0, 0, 0);
      if (row < GN) val = *(const uint4*)(ln + (size_t)row * MD + k0 + seg * 8);
      *(uint4*)&As[r][seg * 8] = val;
    }
    // stage B: 256x64 bf16 = 2048 chunks -> 4 each
#pragma unroll
    for (int cc = 0; cc < 4; ++cc) {
      int c = t + cc * 512;
      int n = c >> 3, seg = c & 7;
      *(uint4*)&Bs[n][seg * 8] = *(const uint4*)(wkv + (size_t)(jb + n) * MD + k0 + seg * 8);
    }
    __syncthreads();
#pragma unroll
    for (int kk = 0; kk < 64; kk += 32) {
      bf16x8 af[4], bfr[4];
#pragma unroll
      for (int tm = 0; tm < 4; ++tm)
        af[tm] = *(const bf16x8*)&As[wm + tm * 16 + l16][kk + quad * 8];
#pragma unroll
      for (int tn = 0; tn < 4; ++tn)
        bfr[tn] = *(const bf16x8*)&Bs[wn + tn * 16 + l16][kk + quad * 8];
#pragma unroll
      for (int tm = 0; tm < 4; ++tm)
#pragma unroll
        for (int tn = 0; tn < 4; ++tn)
          acc[tm][tn] = __builtin_amdgcn_mfma_f32_16x16x32_bf16(af[tm], bfr[tn], acc[tm][tn], 0, 0, 0);
    }
    __syncthreads();
  }
  // epilogue: D row = quad*4+reg (M), col = l16 (N)
#pragma unroll
  for (int tm = 0; tm < 4; ++tm) {
#pragma unroll
    for (int tn = 0; tn < 4; ++tn) {
      int lc = wn + tn * 16 + l16;          // 0..255
      int hh = lc >> 6;
      int dd = lc & 63;
#pragma unroll
      for (int rg = 0; rg < 4; ++rg) {
        int i = i0 + wm + tm * 16 + quad * 4 + rg;
        if (i < GN) obuf[((size_t)hh * GN + i) * HD + dd] = f2bf(acc[tm][tn][rg]);
      }
    }
  }
}

// z[bh][i] = 0.5*beta[h]*xi[b,h,:].K[h,i,:]; per-wave block max -> bmax (no atomics)
__global__ __launch_bounds__(256) void scores_k(const u16* __restrict__ Kbuf, const float* __restrict__ xi,
                                                const float* __restrict__ beta, float* __restrict__ z,
                                                float* __restrict__ bmax) {
  int h = blockIdx.y;
  int row0 = blockIdx.x * 64;
  int t = threadIdx.x;
  __shared__ u16 Ks[64][72];
  __shared__ float xis[8][64];
  {
    int f = t;
    xis[f >> 6][f & 63] = xi[(f >> 6) * 256 + h * 64 + (f & 63)];
    f = t + 256;
    xis[f >> 6][f & 63] = xi[(f >> 6) * 256 + h * 64 + (f & 63)];
  }
  {
    int r = t >> 3, d0 = (t & 7) * 8;
#pragma unroll
    for (int rr = 0; rr < 2; ++rr) {
      int ri = r + rr * 32;
      int row = row0 + ri;
      uint4 val = make_uint4(0, 0, 0, 0);
      if (row < GN) val = *(const uint4*)(Kbuf + ((size_t)h * GN + row) * HD + d0);
      *(uint4*)&Ks[ri][d0] = val;
    }
  }
  __syncthreads();
  int i = t & 63, bg = t >> 6;
  float a0 = 0.f, a1 = 0.f;
#pragma unroll
  for (int dd = 0; dd < 64; dd += 4) {
    ushort4 k4 = *(const ushort4*)&Ks[i][dd];
    float4 x0 = *(const float4*)&xis[bg][dd];
    float4 x1 = *(const float4*)&xis[bg + 4][dd];
    float k0 = bf2f(k4.x), k1 = bf2f(k4.y), k2 = bf2f(k4.z), k3 = bf2f(k4.w);
    a0 += k0 * x0.x + k1 * x0.y + k2 * x0.z + k3 * x0.w;
    a1 += k0 * x1.x + k1 * x1.y + k2 * x1.z + k3 * x1.w;
  }
  float bh = beta[h];
  float z0 = 0.5f * bh * a0;
  float z1 = 0.5f * bh * a1;
  int row = row0 + i;
  if (row < GN) {
    z[((size_t)(bg * 4 + h)) * GN + row] = z0;
    z[((size_t)((bg + 4) * 4 + h)) * GN + row] = z1;
  } else {
    z0 = -1e30f; z1 = -1e30f;
  }
  for (int o = 32; o > 0; o >>= 1) {
    z0 = fmaxf(z0, __shfl_down(z0, o));
    z1 = fmaxf(z1, __shfl_down(z1, o));
  }
  if (i == 0) {
    bmax[(size_t)(bg * 4 + h) * NBLK + blockIdx.x] = z0;
    bmax[(size_t)((bg + 4) * 4 + h) * NBLK + blockIdx.x] = z1;
  }
}

// Fused entmax solve, histogram-only (no candidate list, no Newton):
//  tau* in [gmax-1, gmax]. Level-1: 256-bin histogram of (cnt, sum d, sum d^2),
//  d = u - bin_edge (shifted moments -> no cancellation). Stable top-down scan
//  via frame-shift recurrence finds bracket bin j1 + exact above aggregates.
//  Level-2: 256 sub-bins inside j1 (width 1/65536), same scan seeded with the
//  level-1 aggregates; closed-form quadratic at the crossing sub-bin.
//  Ignored-in-final-subbin error <= 5e4*W2^2 ~ 1.2e-5 in S2 -> dtau <= ~6e-6.
//  One block per bh; 2 passes over z. Also zeroes xi_out.
__global__ __launch_bounds__(1024) void entsolve_k(const float* __restrict__ z,
                                                   const float* __restrict__ bmax,
                                                   float* __restrict__ T, float* __restrict__ xout) {
  int bh = blockIdx.x;
  int t = threadIdx.x, w = t >> 6, lane = t & 63;
  // 8 replicas, row stride 261 (261%32=5 -> replicas on distinct banks; array
  // bases 0/2088/4176 floats -> banks +8/+16 between the three quantities).
  __shared__ float hc[8][261];
  __shared__ float hs[8][261];
  __shared__ float hq[8][261];
  __shared__ float red[16];
  __shared__ float sh_tau;
  __shared__ int   sh_j1;
  __shared__ float sh_E0, sh_E1, sh_E2;
  int rep = w >> 1;
  // zero hists
  for (int i = t; i < 8 * 261; i += 1024) {
    hc[i / 261][i % 261] = 0.f; hs[i / 261][i % 261] = 0.f; hq[i / 261][i % 261] = 0.f;
  }
  // gmax over bmax[bh][.]
  float m = -1e30f;
  for (int i = t; i < NBLK; i += 1024) m = fmaxf(m, bmax[(size_t)bh * NBLK + i]);
  for (int o = 32; o > 0; o >>= 1) m = fmaxf(m, __shfl_down(m, o));
  if (lane == 0) red[w] = m;
  __syncthreads();                       // covers hist zero + red writes
  float gmx = red[0];
#pragma unroll
  for (int q = 1; q < 16; ++q) gmx = fmaxf(gmx, red[q]);
  float lo = gmx - 1.f;
  const float4* zp4 = (const float4*)(z + (size_t)bh * GN);   // 12500 float4
  // ---- pass 1: level-1 histogram, shifted moments, run-length cache ----
  {
    int cidx = -1; float cc = 0.f, cs = 0.f, cq = 0.f;
    for (int i = t; i < 12500; i += 1024) {
      float4 v = zp4[i];
      float va[4] = {v.x, v.y, v.z, v.w};
#pragma unroll
      for (int e = 0; e < 4; ++e) {
        float u = va[e] - lo;
        if (u > 0.f) {
          int idx = (int)(u * 256.f); idx = idx > 255 ? 255 : idx;
          float d = u - (float)idx * W1F;
          if (idx != cidx) {
            if (cidx >= 0) {
              atomicAdd(&hc[rep][cidx], cc); atomicAdd(&hs[rep][cidx], cs); atomicAdd(&hq[rep][cidx], cq);
            }
            cidx = idx; cc = 0.f; cs = 0.f; cq = 0.f;
          }
          cc += 1.f; cs += d; cq += d * d;
        }
      }
    }
    if (cidx >= 0) {
      atomicAdd(&hc[rep][cidx], cc); atomicAdd(&hs[rep][cidx], cs); atomicAdd(&hq[rep][cidx], cq);
    }
  }
  __syncthreads();
  // merge replicas into replica 0
  if (t < NB1) {
    float c = 0.f, s = 0.f, q = 0.f;
#pragma unroll
    for (int r = 0; r < 8; ++r) { c += hc[r][t]; s += hs[r][t]; q += hq[r][t]; }
    hc[0][t] = c; hs[0][t] = s; hq[0][t] = q;
  }
  __syncthreads();
  // level-1 scan (stable incremental frame shift); s2 exact at bin boundaries
  if (t == 0) {
    float TQ = 0.f, TS0 = 0.f, TS1 = 0.f, TC0 = 0.f, TC1 = 0.f, TC2 = 0.f;
    float pE0 = 0.f, pE1 = 0.f, pE2 = 0.f;
    int j1 = 0;
    for (int j = NB1 - 1; j >= 0; --j) {
      TS1 += TS0; TC2 += 2.f * TC1 + TC0; TC1 += TC0;   // advance frame to t_j
      TQ += hq[0][j]; TS0 += hs[0][j]; TC0 += hc[0][j]; // add bin j (m=0)
      float s2 = TQ + 2.f * W1F * TS1 + W1F * W1F * TC2;
      if (s2 >= 1.f) { j1 = j; break; }
      if (j > 0) { pE0 = TC0; pE1 = TS0 + W1F * TC1; pE2 = s2; }  // incl state @ t_j
    }
    sh_j1 = j1; sh_E0 = pE0; sh_E1 = pE1; sh_E2 = pE2;
  }
  __syncthreads();
  int j1 = sh_j1;
  float E0 = sh_E0, E1 = sh_E1, E2 = sh_E2;
  float t1 = (float)j1 * W1F;
  __syncthreads();
  // re-zero hists for level 2
  for (int i = t; i < 8 * 261; i += 1024) {
    hc[i / 261][i % 261] = 0.f; hs[i / 261][i % 261] = 0.f; hq[i / 261][i % 261] = 0.f;
  }
  __syncthreads();
  // ---- pass 2: sub-histogram of bin j1 ----
  {
    int cidx = -1; float cc = 0.f, cs = 0.f, cq = 0.f;
    for (int i = t; i < 12500; i += 1024) {
      float4 v = zp4[i];
      float va[4] = {v.x, v.y, v.z, v.w};
#pragma unroll
      for (int e = 0; e < 4; ++e) {
        float u = va[e] - lo;
        if (u > 0.f) {
          int idx = (int)(u * 256.f); idx = idx > 255 ? 255 : idx;
          if (idx == j1) {
            float d = u - t1;
            int sb = (int)(d * 65536.f); sb = sb > 255 ? 255 : sb;
            float d2 = d - (float)sb * W2F;
            if (sb != cidx) {
              if (cidx >= 0) {
                atomicAdd(&hc[rep][cidx], cc); atomicAdd(&hs[rep][cidx], cs); atomicAdd(&hq[rep][cidx], cq);
              }
              cidx = sb; cc = 0.f; cs = 0.f; cq = 0.f;
            }
            cc += 1.f; cs += d2; cq += d2 * d2;
          }
        }
      }
    }
    if (cidx >= 0) {
      atomicAdd(&hc[rep][cidx], cc); atomicAdd(&hs[rep][cidx], cs); atomicAdd(&hq[rep][cidx], cq);
    }
  }
  __syncthreads();
  if (t < NB1) {
    float c = 0.f, s = 0.f, q = 0.f;
#pragma unroll
    for (int r = 0; r < 8; ++r) { c += hc[r][t]; s += hs[r][t]; q += hq[r][t]; }
    hc[0][t] = c; hs[0][t] = s; hq[0][t] = q;
  }
  __syncthreads();
  // level-2 scan seeded with level-1 aggregates + closed-form quadratic
  if (t == 0) {
    float TQ = E2, TS0 = E1, TS1 = 0.f, TC0 = E0, TC1 = 0.f, TC2 = 0.f;
    float exA = 0.f, exS = 0.f, exQ = 0.f;
    int j2 = 0;
    for (int k = NB1 - 1; k >= 0; --k) {
      TS1 += TS0; TC2 += 2.f * TC1 + TC0; TC1 += TC0;   // advance frame
      exA = TC0;                                        // exclusive-above at t_k
      exS = TS0 + W2F * TC1;
      exQ = TQ + 2.f * W2F * TS1 + W2F * W2F * TC2;
      TQ += hq[0][k]; TS0 += hs[0][k]; TC0 += hc[0][k]; // add sub-bin k
      float s2 = TQ + 2.f * W2F * TS1 + W2F * W2F * TC2;
      if (s2 >= 1.f) { j2 = k; break; }
    }
    float dlt = 0.f;
    if (exA >= 0.5f) {
      float arg = exS * exS - exA * (exQ - 1.f);
      arg = fmaxf(arg, 0.f);
      dlt = (exS - sqrtf(arg)) / exA;   // root of exQ - 2*dlt*exS + dlt^2*exA = 1
    }
    sh_tau = lo + t1 + (float)j2 * W2F + dlt;
  }
  __syncthreads();
  if (t == 0) T[bh] = sh_tau;
  if (t < 64) xout[bh * 64 + t] = 0.f;
}

// xi_new[b,h,d] += sum_i ((z-T)+)^2 * V[h,i,d]; skip all-zero groups of 8 rows
__global__ __launch_bounds__(512) void xiupd_k(const float* __restrict__ z, const float* __restrict__ T,
                                               const u16* __restrict__ Vbuf, float* __restrict__ xi_new) {
  int h = blockIdx.y;
  int row0 = blockIdx.x * 1024;
  int t = threadIdx.x;
  int b = t >> 6, d = t & 63;
  __shared__ float zs[8][1024];
#pragma unroll
  for (int j = 0; j < 16; ++j) {
    int f = t + j * 512;
    int bb = f >> 10, i = f & 1023;
    int row = row0 + i;
    zs[bb][i] = (row < GN) ? z[((size_t)(bb * 4 + h)) * GN + row] : -1e30f;
  }
  __syncthreads();
  float Tv = T[b * 4 + h];
  float acc = 0.f;
  for (int ii = 0; ii < 1024; ii += 8) {
    float wv[8];
#pragma unroll
    for (int e = 0; e < 8; ++e) wv[e] = zs[b][ii + e] - Tv;
    float m8 = wv[0];
#pragma unroll
    for (int e = 1; e < 8; ++e) m8 = fmaxf(m8, wv[e]);
    if (m8 <= 0.f) continue;
    const u16* vrow = Vbuf + ((size_t)h * GN + row0 + ii) * HD + d;
#pragma unroll
    for (int e = 0; e < 8; ++e) {
      float we = fmaxf(wv[e], 0.f);
      float v = bf2f(vrow[e * HD]);
      acc += we * we * v;
    }
  }
  atomicAdd(&xi_new[b * 256 + h * 64 + d], acc);
}

__global__ __launch_bounds__(256) void finout_k(const float* __restrict__ xi, const float* __restrict__ Wo,
                                                float* __restrict__ outs) {
  int w = threadIdx.x >> 6, lane = threadIdx.x & 63;
  int flat = blockIdx.x * 4 + w;
  int b = flat >> 11, o = flat & 2047;
  const float4* wp = (const float4*)(Wo + (size_t)o * 256);
  const float4* xp = (const float4*)(xi + b * 256);
  float4 w4 = wp[lane];
  float4 x4 = xp[lane];
  float acc = w4.x * x4.x + w4.y * x4.y + w4.z * x4.z + w4.w * x4.w;
  for (int o2 = 32; o2 > 0; o2 >>= 1) acc += __shfl_down(acc, o2);
  if (lane == 0) outs[flat] = acc;
}

__global__ __launch_bounds__(256) void bcast_k(const float* __restrict__ outs, float* __restrict__ out) {
  int idx = blockIdx.x * 256 + threadIdx.x;   // float4 index; rows are 512 float4
  int row = idx >> 9, o = idx & 511;
  int b = row >> 11;
  ((float4*)out)[idx] = ((const float4*)outs)[b * 512 + o];
}

// ---------------- launch ----------------
extern "C" void kernel_launch(void* const* d_in, const int* in_sizes, int n_in,
                              void* d_out, int out_size, void* d_ws, size_t ws_size,
                              hipStream_t stream) {
  const float* qe = (const float*)d_in[1];
  const float* mb = (const float*)d_in[2];
  const float* Wq = (const float*)d_in[3];
  const float* Wk = (const float*)d_in[4];
  const float* Wv = (const float*)d_in[5];
  const float* Wo = (const float*)d_in[6];
  const float* lb = (const float*)d_in[7];
  const float* gq = (const float*)d_in[8];
  const float* bq = (const float*)d_in[9];
  const float* gm = (const float*)d_in[10];
  const float* bm = (const float*)d_in[11];

  char* ob = (char*)d_out;
  u16*   ln    = (u16*)(ob + LN_OFF);
  float* z     = (float*)(ob + Z_OFF);
  u16*   Kb    = (u16*)(ob + K_OFF);
  u16*   Vb    = (u16*)(ob + V_OFF);
  u16*   wkv   = (u16*)(ob + WKV_OFF);
  float* bmax  = (float*)(ob + BMAX_OFF);

  char* ws = (char*)d_ws;
  float* xiA  = (float*)(ws + XIA_OFF);
  float* xiB  = (float*)(ws + XIB_OFF);
  float* T    = (float*)(ws + T_OFF);
  float* beta = (float*)(ws + BETA_OFF);
  float* outs = (float*)(ws + OUTS_OFF);

  row_ln<<<12500, 256, 0, stream>>>(mb, gm, bm, ln);
  wconv<<<384, 256, 0, stream>>>(Wk, Wv, wkv);
  qprep<<<8, 256, 0, stream>>>(qe, Wq, gq, bq, lb, xiA, beta);
  gemm_kv<<<dim3(391, 2), 512, 0, stream>>>(ln, wkv, Kb, Vb);

  float* xin = xiA;
  float* xout = xiB;
  for (int s = 0; s < 3; ++s) {
    scores_k<<<dim3(782, 4), 256, 0, stream>>>(Kb, xin, beta, z, bmax);
    entsolve_k<<<32, 1024, 0, stream>>>(z, bmax, T, xout);
    xiupd_k<<<dim3(49, 4), 512, 0, stream>>>(z, T, Vb, xout);
    float* tmp = xin; xin = xout; xout = tmp;
  }

  finout_k<<<4096, 256, 0, stream>>>(xin, Wo, outs);
  bcast_k<<<32768, 256, 0, stream>>>(outs, (float*)d_out);
}

// Round 6
// 779.452 us; speedup vs baseline: 1.5871x; 1.5871x over previous
//
#include <hip/hip_runtime.h>

// QueryPinnedHopfieldLayer on MI355X (gfx950). fp32 in/out; internal K/V bf16.
// d_out (134.2 MB) doubles as scratch: ln_mb bf16 (76.8 MB, aliased by z after
// gemm), ph1/ph2 hist partials (1.6 MB), K (25.6), V (25.6), wkv (0.79), bmax.
//
// Round-10 changes vs round-9 (1237 us; entsolve_k = 3x223 us):
//  KEY EVIDENCE: r8 (26-pass Newton) and r9 (2-pass closed-form) entsolve cost
//  the SAME (232 vs 223 us) with identical FETCH (3.2 MB) and VALUBusy (0.6%).
//  The shared factor is the 32-block x 1024-thread shape streaming z at
//  ~14 GB/s -- the launch shape is the floor, not the inner algorithm.
//  FIX: all z-streaming moved to full-grid kernels; grid=32 kernels now touch
//  only O(256) bins:
//    ehist1_k  (8,32)x256: level-1 256-bin shifted-moment partials -> ph1.
//    esolve1_k (32)x256:   merge, double frame-shift scan -> ep=(lo,j1,E0..E2).
//    ehist2_k  (8,32)x256: level-2 sub-bin partials of bin j1 -> ph2.
//    esolve2_k (32)x256:   merge, seeded scan + quadratic -> T; zero xi_out.
//  Math identical to r9's verified two-level histogram (scans now double).
//  Also: gemm_kv reverted to r7 BM=64 (r8's BM=128 suspected ~+80 us).

typedef unsigned short u16;
typedef unsigned int u32;

typedef __bf16 bf16x8 __attribute__((ext_vector_type(8)));
typedef float f32x4 __attribute__((ext_vector_type(4)));

#define GN 50000
#define NH 4
#define HD 64
#define NB 8
#define MD 768
#define HID 2048
#define NBLK 782
#define NB1 256
#define W1F (1.f/256.f)
#define W2F (1.f/65536.f)
#define HCH 8

__device__ __forceinline__ float bf2f(u16 u) {
  union { u32 i; float f; } v; v.i = ((u32)u) << 16; return v.f;
}
__device__ __forceinline__ u16 f2bf(float f) {
  u32 x = __float_as_uint(f);
  u32 r = (x + 0x7FFFu + ((x >> 16) & 1u)) >> 16;
  return (u16)r;
}

// ---- scratch layout inside d_out (bytes; 16B aligned) ----
#define LN_OFF    0ull           // 50000*768 bf16 = 76.8 MB (dead after gemm)
#define Z_OFF     0ull           // 32*50000 f32 = 6.4 MB (aliases LN)
#define PH1_OFF   6400000ull     // 8*32*768 f32 = 786 KB
#define PH2_OFF   7400000ull     // 8*32*768 f32 = 786 KB -> ends 8.2 MB
#define K_OFF     76800000ull    // 4*50000*64 bf16
#define V_OFF     102400000ull
#define WKV_OFF   128000000ull   // 512*768 bf16
#define BMAX_OFF  128786432ull   // 32*782 f32 -> ends 128.9 MB < 134.2 MB
// ---- small state in d_ws (proven >= 82944 B) ----
#define XIA_OFF   0u
#define XIB_OFF   8192u
#define T_OFF     16384u
#define BETA_OFF  16512u
#define OUTS_OFF  16640u         // 8*2048 f32 -> ends 82176
#define EP_OFF    82176u         // 32*6 f32 -> ends 82944 (== proven limit)

// ---------------- kernels ----------------

// LN(memory_bank) -> bf16, one wave per row (row held in registers)
__global__ __launch_bounds__(256) void row_ln(const float* __restrict__ mb,
                                              const float* __restrict__ gm,
                                              const float* __restrict__ bm,
                                              u16* __restrict__ ln) {
  int row = blockIdx.x * 4 + (threadIdx.x >> 6);
  int lane = threadIdx.x & 63;
  const float4* p4 = (const float4*)(mb + (size_t)row * MD);
  float4 v[3];
  float s = 0.f, ss = 0.f;
#pragma unroll
  for (int j = 0; j < 3; ++j) {
    v[j] = p4[lane + 64 * j];
    s += v[j].x + v[j].y + v[j].z + v[j].w;
    ss += v[j].x * v[j].x + v[j].y * v[j].y + v[j].z * v[j].z + v[j].w * v[j].w;
  }
  for (int o = 32; o > 0; o >>= 1) { s += __shfl_down(s, o); ss += __shfl_down(ss, o); }
  s = __shfl(s, 0); ss = __shfl(ss, 0);
  float m = s * (1.f / 768.f);
  float var = ss * (1.f / 768.f) - m * m;
  float r = rsqrtf(fmaxf(var, 0.f) + 1e-5f);
#pragma unroll
  for (int j = 0; j < 3; ++j) {
    float4 g = ((const float4*)gm)[lane + 64 * j];
    float4 b = ((const float4*)bm)[lane + 64 * j];
    ushort4 o4;
    o4.x = f2bf((v[j].x - m) * r * g.x + b.x);
    o4.y = f2bf((v[j].y - m) * r * g.y + b.y);
    o4.z = f2bf((v[j].z - m) * r * g.z + b.z);
    o4.w = f2bf((v[j].w - m) * r * g.w + b.w);
    *(ushort4*)(ln + (size_t)row * MD + (lane + 64 * j) * 4) = o4;
  }
}

// Wk|Wv fp32 -> bf16 (512x768 flat)
__global__ __launch_bounds__(256) void wconv(const float* __restrict__ Wk,
                                             const float* __restrict__ Wv,
                                             u16* __restrict__ wkv) {
  int i = blockIdx.x * 256 + threadIdx.x;   // float4 index, 98304 total
  float4 v = (i < 49152) ? ((const float4*)Wk)[i] : ((const float4*)Wv)[i - 49152];
  ushort4 o;
  o.x = f2bf(v.x); o.y = f2bf(v.y); o.z = f2bf(v.z); o.w = f2bf(v.w);
  ((ushort4*)wkv)[i] = o;
}

__global__ __launch_bounds__(256) void qprep(const float* __restrict__ qe, const float* __restrict__ Wq,
                                             const float* __restrict__ gq, const float* __restrict__ bq,
                                             const float* __restrict__ lb, float* __restrict__ xi0,
                                             float* __restrict__ beta) {
  int b = blockIdx.x, t = threadIdx.x;
  __shared__ float nq[768];
  __shared__ float w1[4], w2[4];
  float s = 0.f, ss = 0.f;
  for (int j = t; j < 768; j += 256) { float x = qe[b * 768 + j]; s += x; ss += x * x; }
  for (int o = 32; o > 0; o >>= 1) { s += __shfl_down(s, o); ss += __shfl_down(ss, o); }
  if ((t & 63) == 0) { w1[t >> 6] = s; w2[t >> 6] = ss; }
  __syncthreads();
  float S = w1[0] + w1[1] + w1[2] + w1[3];
  float SS = w2[0] + w2[1] + w2[2] + w2[3];
  float m = S * (1.f / 768.f);
  float var = SS * (1.f / 768.f) - m * m;
  float r = rsqrtf(fmaxf(var, 0.f) + 1e-5f);
  for (int j = t; j < 768; j += 256) {
    float x = qe[b * 768 + j];
    nq[j] = (x - m) * r * gq[j] + bq[j];
  }
  __syncthreads();
  const float4* wrow = (const float4*)(Wq + (size_t)t * 768);
  float acc = 0.f;
  for (int k = 0; k < 192; ++k) {
    float4 wv = wrow[k];
    acc += nq[k * 4] * wv.x + nq[k * 4 + 1] * wv.y + nq[k * 4 + 2] * wv.z + nq[k * 4 + 3] * wv.w;
  }
  xi0[b * 256 + t] = acc;
  if (b == 0 && t < 4) beta[t] = expf(lb[t]);
}

// C = ln_mb(bf16) @ wkv^T. BM=64, BN=256, BK=64; 4 waves each 64x64. (r7 exact)
__global__ __launch_bounds__(256) void gemm_kv(const u16* __restrict__ ln,
                                               const u16* __restrict__ wkv,
                                               u16* __restrict__ Kbuf, u16* __restrict__ Vbuf) {
  __shared__ u16 As[64][72];
  __shared__ u16 Bs[256][72];
  int t = threadIdx.x;
  int i0 = blockIdx.x * 64;
  int j0 = blockIdx.y;          // 0 -> K, 1 -> V
  int jb = j0 * 256;
  u16* obuf = j0 ? Vbuf : Kbuf;

  int w = t >> 6, lane = t & 63;
  int quad = lane >> 4, l16 = lane & 15;

  f32x4 acc[4][4];
#pragma unroll
  for (int a = 0; a < 4; ++a)
#pragma unroll
    for (int b = 0; b < 4; ++b) { f32x4 zz = {0.f, 0.f, 0.f, 0.f}; acc[a][b] = zz; }

  for (int k0 = 0; k0 < 768; k0 += 64) {
#pragma unroll
    for (int cc = 0; cc < 2; ++cc) {
      int c = t + cc * 256;
      int r = c >> 3, seg = c & 7;
      int row = i0 + r;
      uint4 val = make_uint4(0, 0, 0, 0);
      if (row < GN) val = *(const uint4*)(ln + (size_t)row * MD + k0 + seg * 8);
      *(uint4*)&As[r][seg * 8] = val;
    }
#pragma unroll
    for (int cc = 0; cc < 8; ++cc) {
      int c = t + cc * 256;
      int n = c >> 3, seg = c & 7;
      *(uint4*)&Bs[n][seg * 8] = *(const uint4*)(wkv + (size_t)(jb + n) * MD + k0 + seg * 8);
    }
    __syncthreads();
#pragma unroll
    for (int kk = 0; kk < 64; kk += 32) {
      bf16x8 af[4], bfr[4];
#pragma unroll
      for (int tm = 0; tm < 4; ++tm)
        af[tm] = *(const bf16x8*)&As[tm * 16 + l16][kk + quad * 8];
#pragma unroll
      for (int tn = 0; tn < 4; ++tn)
        bfr[tn] = *(const bf16x8*)&Bs[w * 64 + tn * 16 + l16][kk + quad * 8];
#pragma unroll
      for (int tm = 0; tm < 4; ++tm)
#pragma unroll
        for (int tn = 0; tn < 4; ++tn)
          acc[tm][tn] = __builtin_amdgcn_mfma_f32_16x16x32_bf16(af[tm], bfr[tn], acc[tm][tn], 0, 0, 0);
    }
    __syncthreads();
  }
#pragma unroll
  for (int tm = 0; tm < 4; ++tm) {
#pragma unroll
    for (int tn = 0; tn < 4; ++tn) {
      int lc = w * 64 + tn * 16 + l16;      // 0..255
      int hh = lc >> 6;
      int dd = lc & 63;
#pragma unroll
      for (int rg = 0; rg < 4; ++rg) {
        int i = i0 + tm * 16 + quad * 4 + rg;
        if (i < GN) obuf[((size_t)hh * GN + i) * HD + dd] = f2bf(acc[tm][tn][rg]);
      }
    }
  }
}

// z[bh][i] = 0.5*beta[h]*xi[b,h,:].K[h,i,:]; per-wave block max -> bmax (no atomics)
__global__ __launch_bounds__(256) void scores_k(const u16* __restrict__ Kbuf, const float* __restrict__ xi,
                                                const float* __restrict__ beta, float* __restrict__ z,
                                                float* __restrict__ bmax) {
  int h = blockIdx.y;
  int row0 = blockIdx.x * 64;
  int t = threadIdx.x;
  __shared__ u16 Ks[64][72];
  __shared__ float xis[8][64];
  {
    int f = t;
    xis[f >> 6][f & 63] = xi[(f >> 6) * 256 + h * 64 + (f & 63)];
    f = t + 256;
    xis[f >> 6][f & 63] = xi[(f >> 6) * 256 + h * 64 + (f & 63)];
  }
  {
    int r = t >> 3, d0 = (t & 7) * 8;
#pragma unroll
    for (int rr = 0; rr < 2; ++rr) {
      int ri = r + rr * 32;
      int row = row0 + ri;
      uint4 val = make_uint4(0, 0, 0, 0);
      if (row < GN) val = *(const uint4*)(Kbuf + ((size_t)h * GN + row) * HD + d0);
      *(uint4*)&Ks[ri][d0] = val;
    }
  }
  __syncthreads();
  int i = t & 63, bg = t >> 6;
  float a0 = 0.f, a1 = 0.f;
#pragma unroll
  for (int dd = 0; dd < 64; dd += 4) {
    ushort4 k4 = *(const ushort4*)&Ks[i][dd];
    float4 x0 = *(const float4*)&xis[bg][dd];
    float4 x1 = *(const float4*)&xis[bg + 4][dd];
    float k0 = bf2f(k4.x), k1 = bf2f(k4.y), k2 = bf2f(k4.z), k3 = bf2f(k4.w);
    a0 += k0 * x0.x + k1 * x0.y + k2 * x0.z + k3 * x0.w;
    a1 += k0 * x1.x + k1 * x1.y + k2 * x1.z + k3 * x1.w;
  }
  float bh = beta[h];
  float z0 = 0.5f * bh * a0;
  float z1 = 0.5f * bh * a1;
  int row = row0 + i;
  if (row < GN) {
    z[((size_t)(bg * 4 + h)) * GN + row] = z0;
    z[((size_t)((bg + 4) * 4 + h)) * GN + row] = z1;
  } else {
    z0 = -1e30f; z1 = -1e30f;
  }
  for (int o = 32; o > 0; o >>= 1) {
    z0 = fmaxf(z0, __shfl_down(z0, o));
    z1 = fmaxf(z1, __shfl_down(z1, o));
  }
  if (i == 0) {
    bmax[(size_t)(bg * 4 + h) * NBLK + blockIdx.x] = z0;
    bmax[(size_t)((bg + 4) * 4 + h) * NBLK + blockIdx.x] = z1;
  }
}

// ---- entmax chain (two-level histogram; all z-streaming at full grid) ----

// level-1: 256-bin shifted-moment partial hist. grid (HCH, 32), 256 thr.
__global__ __launch_bounds__(256) void ehist1_k(const float* __restrict__ z,
                                                const float* __restrict__ bmax,
                                                float* __restrict__ ph1) {
  int ch = blockIdx.x, bh = blockIdx.y;
  int t = threadIdx.x, w = t >> 6, lane = t & 63;
  __shared__ float hc[4][NB1], hs[4][NB1], hq[4][NB1];
  __shared__ float red[4];
  for (int i = t; i < 4 * NB1; i += 256) {
    hc[i >> 8][i & 255] = 0.f; hs[i >> 8][i & 255] = 0.f; hq[i >> 8][i & 255] = 0.f;
  }
  float m = -1e30f;
  for (int i = t; i < NBLK; i += 256) m = fmaxf(m, bmax[(size_t)bh * NBLK + i]);
  for (int o = 32; o > 0; o >>= 1) m = fmaxf(m, __shfl_down(m, o));
  if (lane == 0) red[w] = m;
  __syncthreads();                       // covers hist zero + red
  float gmx = fmaxf(fmaxf(red[0], red[1]), fmaxf(red[2], red[3]));
  float lo = gmx - 1.f;
  const float4* zp4 = (const float4*)(z + (size_t)bh * GN);   // 12500 float4
  int rep = w;
  {
    int cidx = -1; float cc = 0.f, cs = 0.f, cq = 0.f;
    for (int i = ch * 256 + t; i < 12500; i += HCH * 256) {
      float4 v = zp4[i];
      float va[4] = {v.x, v.y, v.z, v.w};
#pragma unroll
      for (int e = 0; e < 4; ++e) {
        float u = va[e] - lo;
        if (u > 0.f) {
          int idx = (int)(u * 256.f); idx = idx > 255 ? 255 : idx;
          float d = u - (float)idx * W1F;
          if (idx != cidx) {
            if (cidx >= 0) {
              atomicAdd(&hc[rep][cidx], cc); atomicAdd(&hs[rep][cidx], cs); atomicAdd(&hq[rep][cidx], cq);
            }
            cidx = idx; cc = 0.f; cs = 0.f; cq = 0.f;
          }
          cc += 1.f; cs += d; cq += d * d;
        }
      }
    }
    if (cidx >= 0) {
      atomicAdd(&hc[rep][cidx], cc); atomicAdd(&hs[rep][cidx], cs); atomicAdd(&hq[rep][cidx], cq);
    }
  }
  __syncthreads();
  float* o = ph1 + ((size_t)(ch * 32 + bh)) * 768;
  float c = hc[0][t] + hc[1][t] + hc[2][t] + hc[3][t];
  float s = hs[0][t] + hs[1][t] + hs[2][t] + hs[3][t];
  float q = hq[0][t] + hq[1][t] + hq[2][t] + hq[3][t];
  o[t] = c; o[NB1 + t] = s; o[2 * NB1 + t] = q;
}

// merge level-1 partials; double frame-shift scan -> ep = (lo, j1, E0, E1, E2)
__global__ __launch_bounds__(256) void esolve1_k(const float* __restrict__ ph1,
                                                 const float* __restrict__ bmax,
                                                 float* __restrict__ ep) {
  int bh = blockIdx.x;
  int t = threadIdx.x, w = t >> 6, lane = t & 63;
  __shared__ float hc[NB1], hs[NB1], hq[NB1];
  __shared__ float red[4];
  float c = 0.f, s = 0.f, q = 0.f;
  for (int ch = 0; ch < HCH; ++ch) {
    const float* p = ph1 + ((size_t)(ch * 32 + bh)) * 768;
    c += p[t]; s += p[NB1 + t]; q += p[2 * NB1 + t];
  }
  hc[t] = c; hs[t] = s; hq[t] = q;
  float m = -1e30f;
  for (int i = t; i < NBLK; i += 256) m = fmaxf(m, bmax[(size_t)bh * NBLK + i]);
  for (int o = 32; o > 0; o >>= 1) m = fmaxf(m, __shfl_down(m, o));
  if (lane == 0) red[w] = m;
  __syncthreads();                       // covers hist + red
  float gmx = fmaxf(fmaxf(red[0], red[1]), fmaxf(red[2], red[3]));
  if (t == 0) {
    float lo = gmx - 1.f;
    const double w1 = 1.0 / 256.0;
    double TQ = 0., TS0 = 0., TS1 = 0., TC0 = 0., TC1 = 0., TC2 = 0.;
    double pE0 = 0., pE1 = 0., pE2 = 0.;
    int j1 = 0;
    for (int j = NB1 - 1; j >= 0; --j) {
      TS1 += TS0; TC2 += 2. * TC1 + TC0; TC1 += TC0;
      TQ += (double)hq[j]; TS0 += (double)hs[j]; TC0 += (double)hc[j];
      double s2 = TQ + 2. * w1 * TS1 + w1 * w1 * TC2;
      if (s2 >= 1.) { j1 = j; break; }
      if (j > 0) { pE0 = TC0; pE1 = TS0 + w1 * TC1; pE2 = s2; }
    }
    ep[bh * 6 + 0] = lo;
    ep[bh * 6 + 1] = (float)j1;
    ep[bh * 6 + 2] = (float)pE0;
    ep[bh * 6 + 3] = (float)pE1;
    ep[bh * 6 + 4] = (float)pE2;
  }
}

// level-2: sub-bin partials of bin j1. grid (HCH, 32), 256 thr.
__global__ __launch_bounds__(256) void ehist2_k(const float* __restrict__ z,
                                                const float* __restrict__ ep,
                                                float* __restrict__ ph2) {
  int ch = blockIdx.x, bh = blockIdx.y;
  int t = threadIdx.x, w = t >> 6;
  __shared__ float hc[4][NB1], hs[4][NB1], hq[4][NB1];
  for (int i = t; i < 4 * NB1; i += 256) {
    hc[i >> 8][i & 255] = 0.f; hs[i >> 8][i & 255] = 0.f; hq[i >> 8][i & 255] = 0.f;
  }
  __syncthreads();
  float lo = ep[bh * 6 + 0];
  int j1 = (int)ep[bh * 6 + 1];
  float t1 = (float)j1 * W1F;
  const float4* zp4 = (const float4*)(z + (size_t)bh * GN);
  int rep = w;
  {
    int cidx = -1; float cc = 0.f, cs = 0.f, cq = 0.f;
    for (int i = ch * 256 + t; i < 12500; i += HCH * 256) {
      float4 v = zp4[i];
      float va[4] = {v.x, v.y, v.z, v.w};
#pragma unroll
      for (int e = 0; e < 4; ++e) {
        float u = va[e] - lo;
        if (u > 0.f) {
          int idx = (int)(u * 256.f); idx = idx > 255 ? 255 : idx;
          if (idx == j1) {
            float d = u - t1;
            int sb = (int)(d * 65536.f); sb = sb > 255 ? 255 : sb;
            float d2 = d - (float)sb * W2F;
            if (sb != cidx) {
              if (cidx >= 0) {
                atomicAdd(&hc[rep][cidx], cc); atomicAdd(&hs[rep][cidx], cs); atomicAdd(&hq[rep][cidx], cq);
              }
              cidx = sb; cc = 0.f; cs = 0.f; cq = 0.f;
            }
            cc += 1.f; cs += d2; cq += d2 * d2;
          }
        }
      }
    }
    if (cidx >= 0) {
      atomicAdd(&hc[rep][cidx], cc); atomicAdd(&hs[rep][cidx], cs); atomicAdd(&hq[rep][cidx], cq);
    }
  }
  __syncthreads();
  float* o = ph2 + ((size_t)(ch * 32 + bh)) * 768;
  float c = hc[0][t] + hc[1][t] + hc[2][t] + hc[3][t];
  float s = hs[0][t] + hs[1][t] + hs[2][t] + hs[3][t];
  float q = hq[0][t] + hq[1][t] + hq[2][t] + hq[3][t];
  o[t] = c; o[NB1 + t] = s; o[2 * NB1 + t] = q;
}

// merge level-2 partials; seeded double scan + closed-form quadratic -> T.
// Also zeroes xi_out.
__global__ __launch_bounds__(256) void esolve2_k(const float* __restrict__ ph2,
                                                 const float* __restrict__ ep,
                                                 float* __restrict__ T, float* __restrict__ xout) {
  int bh = blockIdx.x;
  int t = threadIdx.x;
  __shared__ float hc[NB1], hs[NB1], hq[NB1];
  float c = 0.f, s = 0.f, q = 0.f;
  for (int ch = 0; ch < HCH; ++ch) {
    const float* p = ph2 + ((size_t)(ch * 32 + bh)) * 768;
    c += p[t]; s += p[NB1 + t]; q += p[2 * NB1 + t];
  }
  hc[t] = c; hs[t] = s; hq[t] = q;
  __syncthreads();
  if (t == 0) {
    float lo = ep[bh * 6 + 0];
    int j1 = (int)ep[bh * 6 + 1];
    const double w2 = 1.0 / 65536.0;
    double TQ = (double)ep[bh * 6 + 4], TS0 = (double)ep[bh * 6 + 3], TS1 = 0.;
    double TC0 = (double)ep[bh * 6 + 2], TC1 = 0., TC2 = 0.;
    double exA = 0., exS = 0., exQ = 0.;
    int j2 = 0;
    for (int k = NB1 - 1; k >= 0; --k) {
      TS1 += TS0; TC2 += 2. * TC1 + TC0; TC1 += TC0;
      exA = TC0;
      exS = TS0 + w2 * TC1;
      exQ = TQ + 2. * w2 * TS1 + w2 * w2 * TC2;
      TQ += (double)hq[k]; TS0 += (double)hs[k]; TC0 += (double)hc[k];
      double s2 = TQ + 2. * w2 * TS1 + w2 * w2 * TC2;
      if (s2 >= 1.) { j2 = k; break; }
    }
    double dlt = 0.;
    if (exA >= 0.5) {
      double arg = exS * exS - exA * (exQ - 1.);
      if (arg < 0.) arg = 0.;
      dlt = (exS - sqrt(arg)) / exA;
    }
    T[bh] = (float)((double)lo + (double)j1 * (1.0 / 256.0) + (double)j2 * w2 + dlt);
  }
  if (t < 64) xout[bh * 64 + t] = 0.f;
}

// xi_new[b,h,d] += sum_i ((z-T)+)^2 * V[h,i,d]; skip all-zero groups of 8 rows
__global__ __launch_bounds__(512) void xiupd_k(const float* __restrict__ z, const float* __restrict__ T,
                                               const u16* __restrict__ Vbuf, float* __restrict__ xi_new) {
  int h = blockIdx.y;
  int row0 = blockIdx.x * 1024;
  int t = threadIdx.x;
  int b = t >> 6, d = t & 63;
  __shared__ float zs[8][1024];
#pragma unroll
  for (int j = 0; j < 16; ++j) {
    int f = t + j * 512;
    int bb = f >> 10, i = f & 1023;
    int row = row0 + i;
    zs[bb][i] = (row < GN) ? z[((size_t)(bb * 4 + h)) * GN + row] : -1e30f;
  }
  __syncthreads();
  float Tv = T[b * 4 + h];
  float acc = 0.f;
  for (int ii = 0; ii < 1024; ii += 8) {
    float wv[8];
#pragma unroll
    for (int e = 0; e < 8; ++e) wv[e] = zs[b][ii + e] - Tv;
    float m8 = wv[0];
#pragma unroll
    for (int e = 1; e < 8; ++e) m8 = fmaxf(m8, wv[e]);
    if (m8 <= 0.f) continue;
    const u16* vrow = Vbuf + ((size_t)h * GN + row0 + ii) * HD + d;
#pragma unroll
    for (int e = 0; e < 8; ++e) {
      float we = fmaxf(wv[e], 0.f);
      float v = bf2f(vrow[e * HD]);
      acc += we * we * v;
    }
  }
  atomicAdd(&xi_new[b * 256 + h * 64 + d], acc);
}

__global__ __launch_bounds__(256) void finout_k(const float* __restrict__ xi, const float* __restrict__ Wo,
                                                float* __restrict__ outs) {
  int w = threadIdx.x >> 6, lane = threadIdx.x & 63;
  int flat = blockIdx.x * 4 + w;
  int b = flat >> 11, o = flat & 2047;
  const float4* wp = (const float4*)(Wo + (size_t)o * 256);
  const float4* xp = (const float4*)(xi + b * 256);
  float4 w4 = wp[lane];
  float4 x4 = xp[lane];
  float acc = w4.x * x4.x + w4.y * x4.y + w4.z * x4.z + w4.w * x4.w;
  for (int o2 = 32; o2 > 0; o2 >>= 1) acc += __shfl_down(acc, o2);
  if (lane == 0) outs[flat] = acc;
}

__global__ __launch_bounds__(256) void bcast_k(const float* __restrict__ outs, float* __restrict__ out) {
  int idx = blockIdx.x * 256 + threadIdx.x;   // float4 index; rows are 512 float4
  int row = idx >> 9, o = idx & 511;
  int b = row >> 11;
  ((float4*)out)[idx] = ((const float4*)outs)[b * 512 + o];
}

// ---------------- launch ----------------
extern "C" void kernel_launch(void* const* d_in, const int* in_sizes, int n_in,
                              void* d_out, int out_size, void* d_ws, size_t ws_size,
                              hipStream_t stream) {
  const float* qe = (const float*)d_in[1];
  const float* mb = (const float*)d_in[2];
  const float* Wq = (const float*)d_in[3];
  const float* Wk = (const float*)d_in[4];
  const float* Wv = (const float*)d_in[5];
  const float* Wo = (const float*)d_in[6];
  const float* lb = (const float*)d_in[7];
  const float* gq = (const float*)d_in[8];
  const float* bq = (const float*)d_in[9];
  const float* gm = (const float*)d_in[10];
  const float* bm = (const float*)d_in[11];

  char* ob = (char*)d_out;
  u16*   ln    = (u16*)(ob + LN_OFF);
  float* z     = (float*)(ob + Z_OFF);
  float* ph1   = (float*)(ob + PH1_OFF);
  float* ph2   = (float*)(ob + PH2_OFF);
  u16*   Kb    = (u16*)(ob + K_OFF);
  u16*   Vb    = (u16*)(ob + V_OFF);
  u16*   wkv   = (u16*)(ob + WKV_OFF);
  float* bmax  = (float*)(ob + BMAX_OFF);

  char* ws = (char*)d_ws;
  float* xiA  = (float*)(ws + XIA_OFF);
  float* xiB  = (float*)(ws + XIB_OFF);
  float* T    = (float*)(ws + T_OFF);
  float* beta = (float*)(ws + BETA_OFF);
  float* outs = (float*)(ws + OUTS_OFF);
  float* ep   = (float*)(ws + EP_OFF);

  row_ln<<<12500, 256, 0, stream>>>(mb, gm, bm, ln);
  wconv<<<384, 256, 0, stream>>>(Wk, Wv, wkv);
  qprep<<<8, 256, 0, stream>>>(qe, Wq, gq, bq, lb, xiA, beta);
  gemm_kv<<<dim3(782, 2), 256, 0, stream>>>(ln, wkv, Kb, Vb);

  float* xin = xiA;
  float* xout = xiB;
  for (int s = 0; s < 3; ++s) {
    scores_k<<<dim3(782, 4), 256, 0, stream>>>(Kb, xin, beta, z, bmax);
    ehist1_k<<<dim3(HCH, 32), 256, 0, stream>>>(z, bmax, ph1);
    esolve1_k<<<32, 256, 0, stream>>>(ph1, bmax, ep);
    ehist2_k<<<dim3(HCH, 32), 256, 0, stream>>>(z, ep, ph2);
    esolve2_k<<<32, 256, 0, stream>>>(ph2, ep, T, xout);
    xiupd_k<<<dim3(49, 4), 512, 0, stream>>>(z, T, Vb, xout);
    float* tmp = xin; xin = xout; xout = tmp;
  }

  finout_k<<<4096, 256, 0, stream>>>(xin, Wo, outs);
  bcast_k<<<32768, 256, 0, stream>>>(outs, (float*)d_out);
}